// Round 12
// baseline (358.268 us; speedup 1.0000x reference)
//
#include <hip/hip_runtime.h>
#include <stdint.h>

#define DEV __device__ __forceinline__

typedef unsigned short u16;
typedef unsigned int u32;
typedef unsigned char u8;

typedef __bf16 bf16x8 __attribute__((ext_vector_type(8)));
typedef float f32x4 __attribute__((ext_vector_type(4)));
typedef u16 u16x8 __attribute__((ext_vector_type(8)));
typedef u16 u16x4 __attribute__((ext_vector_type(4)));
typedef u8 u8x8 __attribute__((ext_vector_type(8)));
typedef int i32x4 __attribute__((ext_vector_type(4)));
typedef int i32x8 __attribute__((ext_vector_type(8)));

static_assert(sizeof(bf16x8) == 16, "bf16x8 must be 16B");
static_assert(sizeof(i32x8) == 32, "i32x8 must be 32B");

#define NT 16384      // B*S = 4*4096
#define SPAD 4098     // S + 2 halo rows per batch

DEV u16 f2bf(float f) {
  u32 u = __float_as_uint(f);
  u32 r = u + 0x7FFFu + ((u >> 16) & 1u);
  return (u16)(r >> 16);
}
DEV float bf2f(u16 h) { return __uint_as_float(((u32)h) << 16); }
DEV float siluf(float x) { return x / (1.f + __expf(-x)); }

// tanh-gelu: used ONLY on the softmax-logit path (conv output, P-gelu)
DEV float gelu_t(float x) {
  float x2 = x * x;
  float z2 = x * (1.5957691216f + 0.0713548162f * x2);
  return x / (1.f + __expf(-z2));
}

// 2x f32 -> packed OCP e4m3 in low 16 bits (HW RNE+sat). low byte = src0.
DEV u32 cvtpk8(float a, float b) {
  u32 r;
  asm("v_cvt_pk_fp8_f32 %0, %1, %2" : "=v"(r) : "v"(a), "v"(b));
  return r;
}

DEV void gload_lds16(const void* g, void* l) {
  __builtin_amdgcn_global_load_lds((const __attribute__((address_space(1))) void*)g,
                                   (__attribute__((address_space(3))) void*)l,
                                   16, 0, 0);
}

DEV f32x4 mfma_mx(i32x8 a, i32x8 b, f32x4 c) {
  // fp8(e4m3) x fp8, unit scales (E8M0 127 = 2^0)
  return __builtin_amdgcn_mfma_scale_f32_16x16x128_f8f6f4(
      a, b, c, 0, 0, 0, 0x7F7F7F7Fu, 0, 0x7F7F7F7Fu);
}

// ---------------- merged converts ----------------
// [0,16384): x f32 -> XB bf16
// [16384,20480): Wq/Wo/Wg/Wout -> bf16 WALL
// [20480,22528): wa,wb -> fp8 WAB8
// [22528,26624): conv_w -> fp8 WC8 (tap-major)
// [26624,26656): zero halo rows of QPAD (bf16) and QPAD8 (fp8)
__global__ void cvt_misc(const float* __restrict__ x,
                         const float* __restrict__ Wq, const float* __restrict__ Wo,
                         const float* __restrict__ Wg, const float* __restrict__ Wout,
                         const float* __restrict__ wa, const float* __restrict__ wb,
                         const float* __restrict__ cw,
                         u16* __restrict__ XB,
                         u16* __restrict__ WALL, u8* __restrict__ WAB8,
                         u8* __restrict__ WC8, u16* __restrict__ QPAD,
                         u8* __restrict__ QPAD8)
{
  int bid = blockIdx.x, tid = threadIdx.x;
  if (bid < 16384) {
    int i = bid * 256 + tid;                        // 4,194,304 four-elem groups
    const float4 v = *(const float4*)(x + (size_t)i * 4);
    u16x4 o;
    o[0] = f2bf(v.x); o[1] = f2bf(v.y); o[2] = f2bf(v.z); o[3] = f2bf(v.w);
    *(u16x4*)(XB + (size_t)i * 4) = o;
  } else if (bid < 20480) {
    int idx = (bid - 16384) * 256 + tid;            // 4 * 262144
    int mat = idx >> 18, within = idx & 262143;
    const float* src = (mat == 0) ? Wq : (mat == 1) ? Wo : (mat == 2) ? Wg : Wout;
    const float4 v = *(const float4*)(src + (size_t)within * 4);
    u16x4 o;
    o[0] = f2bf(v.x); o[1] = f2bf(v.y); o[2] = f2bf(v.z); o[3] = f2bf(v.w);
    *(u16x4*)(WALL + (size_t)idx * 4) = o;
  } else if (bid < 22528) {
    int idx = (bid - 20480) * 256 + tid;            // 2 * 262144
    const float* src = (idx >> 18) ? wb : wa;
    int within = idx & 262143;
    const float4 v = *(const float4*)(src + (size_t)within * 4);
    u32 o = (cvtpk8(v.x, v.y) & 0xFFFFu) | (cvtpk8(v.z, v.w) << 16);
    *(u32*)(WAB8 + (size_t)idx * 4) = o;
  } else if (bid < 26624) {
    int i = (bid - 22528) * 256 + tid;              // 1M: o*1024+d
    int o = i >> 10, d = i & 1023;
    const float* src = cw + ((size_t)o * 1024 + d) * 3;
    u8* dst = WC8 + (size_t)o * 3072 + d;
    u32 w01 = cvtpk8(src[0], src[1]);
    u32 w2  = cvtpk8(src[2], src[2]);
    dst[0]    = (u8)(w01 & 0xFF);
    dst[1024] = (u8)((w01 >> 8) & 0xFF);
    dst[2048] = (u8)(w2 & 0xFF);
  } else {
    int i = (bid - 26624) * 256 + tid;              // 8192 threads
    int r = i >> 10, c = i & 1023;
    int b = r >> 1, side = r & 1;
    size_t row = (size_t)b * SPAD + (side ? (SPAD - 1) : 0);
    QPAD[row * 1024 + c] = 0;
    QPAD8[row * 1024 + c] = 0;
  }
}

// ================= gemm128: PROVEN bf16 structure (~888 TF) =================
// MODE 0: bf16 out (+bias). MODE 1: bf16 halo out + fp8 halo out to C2 (+bias).
// MODE 3: f32 out (+bias).
template<int MODE>
__global__ __launch_bounds__(256, 2)
void gemm128(const u16* __restrict__ A, const u16* __restrict__ B,
             void* __restrict__ C, void* __restrict__ C2, const float* __restrict__ bias,
             int M, int N, int K, int lda)
{
  __shared__ alignas(16) char smem[32768];
  char* sA = smem;
  char* sB = smem + 16384;

  int nwg = gridDim.x;
  int bx = blockIdx.x;
  if ((nwg & 7) == 0) bx = (bx & 7) * (nwg >> 3) + (bx >> 3);  // XCD swizzle (bijective)
  int GN = N >> 7;
  int bm = bx / GN, bn = bx - bm * GN;
  int m0 = bm << 7, n0 = bn << 7;

  int tid = threadIdx.x;
  int lane = tid & 63, wid = tid >> 6;
  int wm = wid >> 1, wn = wid & 1;

  f32x4 acc[4][4] = {};

  int strow = tid >> 3;            // 0..31
  int stcolb = (tid & 7) << 4;     // byte col 0..112
  size_t ldab = (size_t)lda * 2;
  size_t ldbb = (size_t)K * 2;

  const int KT = K >> 6;
  for (int kt = 0; kt < KT; ++kt) {
    int k0 = kt << 6;
    const char* Ab = (const char*)(A + ((size_t)m0 * (size_t)lda + k0));
    const char* Bb = (const char*)(B + ((size_t)n0 * (size_t)K + k0));
#pragma unroll
    for (int j = 0; j < 4; ++j) {
      int row = j * 32 + strow;
      int sw = (row & 7) << 4;     // XOR swizzle on 16B granules (involution)
      gload_lds16(Ab + (size_t)row * ldab + (size_t)(stcolb ^ sw), sA + j * 4096 + wid * 1024);
      gload_lds16(Bb + (size_t)row * ldbb + (size_t)(stcolb ^ sw), sB + j * 4096 + wid * 1024);
    }
    __syncthreads();
#pragma unroll
    for (int kk = 0; kk < 2; ++kk) {
      bf16x8 av[4], bv[4];
      int cb = ((lane >> 4) << 4) + (kk << 6);
#pragma unroll
      for (int i = 0; i < 4; ++i) {
        int r = (wm << 6) + (i << 4) + (lane & 15);
        av[i] = *(const bf16x8*)(sA + r * 128 + (cb ^ ((r & 7) << 4)));
      }
#pragma unroll
      for (int j = 0; j < 4; ++j) {
        int r = (wn << 6) + (j << 4) + (lane & 15);
        bv[j] = *(const bf16x8*)(sB + r * 128 + (cb ^ ((r & 7) << 4)));
      }
#pragma unroll
      for (int i = 0; i < 4; ++i)
#pragma unroll
        for (int j = 0; j < 4; ++j)
          acc[i][j] = __builtin_amdgcn_mfma_f32_16x16x32_bf16(av[i], bv[j], acc[i][j], 0, 0, 0);
    }
    __syncthreads();
  }

  // epilogue: frag row=(lane>>4)*4+r, col=lane&15
#pragma unroll
  for (int i = 0; i < 4; ++i) {
    int rb = m0 + (wm << 6) + (i << 4) + ((lane >> 4) << 2);
#pragma unroll
    for (int j = 0; j < 4; ++j) {
      int n = n0 + (wn << 6) + (j << 4) + (lane & 15);
      float bs = bias ? bias[n] : 0.f;
      if (MODE == 1) {
        // bf16 halo + fp8 halo dual write (rows rb..rb+3 same batch, halo rows consecutive)
        float v0 = acc[i][j][0] + bs, v1 = acc[i][j][1] + bs;
        float v2 = acc[i][j][2] + bs, v3 = acc[i][j][3] + bs;
        size_t row0 = (size_t)rb + 2 * (rb >> 12) + 1;
        u16* cb16 = (u16*)C + row0 * 1024 + n;
        cb16[0]    = f2bf(v0);
        cb16[1024] = f2bf(v1);
        cb16[2048] = f2bf(v2);
        cb16[3072] = f2bf(v3);
        u32 w01 = cvtpk8(v0, v1);
        u32 w23 = cvtpk8(v2, v3);
        u8* c8 = (u8*)C2 + row0 * 1024 + n;
        c8[0]    = (u8)(w01 & 0xFF);
        c8[1024] = (u8)((w01 >> 8) & 0xFF);
        c8[2048] = (u8)(w23 & 0xFF);
        c8[3072] = (u8)((w23 >> 8) & 0xFF);
      } else {
#pragma unroll
        for (int r = 0; r < 4; ++r) {
          int t = rb + r;
          float v = acc[i][j][r] + bs;
          if (MODE == 0) ((u16*)C)[(size_t)t * N + n] = f2bf(v);
          else           ((float*)C)[(size_t)t * N + n] = v;
        }
      }
    }
  }
}

// ================= gemm128f8: MX-fp8, conflict-free half-swizzle, BK=128 =================
// LDS bijection: half h of granule (row r, 32B-col cb) at
//   r*128 + (cb ^ ((r&3)<<5)) + 16*(h ^ ((r>>2)&1)); linear dest, source solves it.
// A addressing is PURELY LINEAR in kt for both modes (conv tap stride 1024B == 8 kt * 128B)
// -> incremental pointers, per-thread kt-invariant offsets.
// MODE 2: conv (A = fp8 Qpad halo, base row m0+2*bofm), epilogue gelu_t(silu(v+b)) -> fp8.
// MODE 5: fused logits+softmax-partial -> PZp/PNp[m_tile][col].
template<int MODE, int VREMAP>
__global__ __launch_bounds__(256, 2)
void gemm128f8(const u8* __restrict__ A, const u8* __restrict__ B,
               void* __restrict__ C, const float* __restrict__ bias, float episcale,
               const u16* __restrict__ vals, float* __restrict__ PZp, float* __restrict__ PNp,
               int M, int N, int K, int lda /*bytes*/)
{
  __shared__ alignas(32) char smem[32768];
  char* sA = smem;
  char* sB = smem + 16384;

  int nwg = gridDim.x;
  int bx = blockIdx.x;
  if ((nwg & 7) == 0) bx = (bx & 7) * (nwg >> 3) + (bx >> 3);
  int GN = N >> 7;
  int bm = bx / GN, bn = bx - bm * GN;
  int m0 = bm << 7, n0 = bn << 7;

  int tid = threadIdx.x;
  int lane = tid & 63, wid = tid >> 6;
  int wm = wid >> 1, wn = wid & 1;

  f32x4 acc[4][4] = {};

  int strow = tid >> 3;            // 0..31 (row within 32-row chunk)
  int g = (tid >> 1) & 3, p = tid & 1;
  int srccol = (((g ^ (strow & 3)) << 5) | ((p ^ ((strow >> 2) & 1)) << 4));
  int bofm = m0 >> 12;

  // incremental bases + kt-invariant per-thread offsets
  const char* Ab = (const char*)A + (size_t)(m0 + (MODE == 2 ? 2 * bofm : 0)) * lda;
  const char* Bb = (const char*)B + (size_t)n0 * K;
  size_t offA[4], offB[4];
#pragma unroll
  for (int j = 0; j < 4; ++j) {
    offA[j] = (size_t)(j * 32 + strow) * lda + srccol;
    offB[j] = (size_t)(j * 32 + strow) * K + srccol;
  }
  int dstL[4];
#pragma unroll
  for (int j = 0; j < 4; ++j) dstL[j] = j * 4096 + wid * 1024;

  const int KT = K >> 7;           // BK = 128 (bytes == elements)
  for (int kt = 0; kt < KT; ++kt) {
#pragma unroll
    for (int j = 0; j < 4; ++j) {
      gload_lds16(Ab + offA[j], sA + dstL[j]);
      gload_lds16(Bb + offB[j], sB + dstL[j]);
    }
    __syncthreads();
    {
      i32x8 av[4], bv[4];
      int cb = (lane >> 4) << 5;   // 32B K-chunk per lane group (one MX block)
#pragma unroll
      for (int i = 0; i < 4; ++i) {
        int r = (wm << 6) + (i << 4) + (lane & 15);
        int base = r * 128 + (cb ^ ((r & 3) << 5));
        int b2 = ((r >> 2) & 1) << 4;
        i32x4 lo = *(const i32x4*)(sA + base + b2);          // half 0
        i32x4 hi = *(const i32x4*)(sA + base + (b2 ^ 16));   // half 1
        av[i] = i32x8{lo[0], lo[1], lo[2], lo[3], hi[0], hi[1], hi[2], hi[3]};
      }
#pragma unroll
      for (int j = 0; j < 4; ++j) {
        int r = (wn << 6) + (j << 4) + (lane & 15);
        int base = r * 128 + (cb ^ ((r & 3) << 5));
        int b2 = ((r >> 2) & 1) << 4;
        i32x4 lo = *(const i32x4*)(sB + base + b2);
        i32x4 hi = *(const i32x4*)(sB + base + (b2 ^ 16));
        bv[j] = i32x8{lo[0], lo[1], lo[2], lo[3], hi[0], hi[1], hi[2], hi[3]};
      }
#pragma unroll
      for (int i = 0; i < 4; ++i)
#pragma unroll
        for (int j = 0; j < 4; ++j)
          acc[i][j] = mfma_mx(av[i], bv[j], acc[i][j]);
    }
    __syncthreads();
    Ab += 128; Bb += 128;          // linear walk (conv taps included)
  }

  if (MODE == 2) {
#pragma unroll
    for (int i = 0; i < 4; ++i) {
      int rb = m0 + (wm << 6) + (i << 4) + ((lane >> 4) << 2);
#pragma unroll
      for (int j = 0; j < 4; ++j) {
        int n = n0 + (wn << 6) + (j << 4) + (lane & 15);
        float bs = bias ? bias[n] : 0.f;
        float g0 = gelu_t(siluf(acc[i][j][0] + bs));
        float g1 = gelu_t(siluf(acc[i][j][1] + bs));
        float g2 = gelu_t(siluf(acc[i][j][2] + bs));
        float g3 = gelu_t(siluf(acc[i][j][3] + bs));
        u32 w01 = cvtpk8(g0, g1);
        u32 w23 = cvtpk8(g2, g3);
        u8* cp = (u8*)C + (size_t)rb * N + n;
        cp[0]            = (u8)(w01 & 0xFF);
        cp[(size_t)N]    = (u8)((w01 >> 8) & 0xFF);
        cp[(size_t)N*2]  = (u8)(w23 & 0xFF);
        cp[(size_t)N*3]  = (u8)((w23 >> 8) & 0xFF);
      }
    }
  } else {  // MODE 5: fused softmax partial (no max subtraction; logits are tiny)
    float zj[4] = {0.f, 0.f, 0.f, 0.f}, nj[4] = {0.f, 0.f, 0.f, 0.f};
#pragma unroll
    for (int i = 0; i < 4; ++i) {
      int rb = m0 + (wm << 6) + (i << 4) + ((lane >> 4) << 2);
#pragma unroll
      for (int j = 0; j < 4; ++j) {
        int n = n0 + (wn << 6) + (j << 4) + (lane & 15);
#pragma unroll
        for (int r = 0; r < 4; ++r) {
          int t = rb + r;
          float w = __expf(acc[i][j][r] * episcale);
          size_t vrow = VREMAP ? ((size_t)t + 2 * (t >> 12) + 1) : (size_t)t;
          float v = bf2f(vals[vrow * 1024 + n]);
          zj[j] += w;
          nj[j] += v * w;
        }
      }
    }
    __syncthreads();                 // LDS free after K-loop's trailing sync + this
    float2* arr = (float2*)smem;     // [128 cols][8 contributors]
    int gg = (wm << 2) + (lane >> 4); // 0..7
#pragma unroll
    for (int j = 0; j < 4; ++j) {
      int cl = (wn << 6) + (j << 4) + (lane & 15);   // 0..127
      arr[cl * 8 + gg] = make_float2(zj[j], nj[j]);
    }
    __syncthreads();
    if (tid < 128) {
      float Z = 0.f, Nn = 0.f;
#pragma unroll
      for (int g2 = 0; g2 < 8; ++g2) { float2 q = arr[tid * 8 + g2]; Z += q.x; Nn += q.y; }
      size_t o = (size_t)(m0 >> 7) * 1024 + n0 + tid;
      PZp[o] = Z;
      PNp[o] = Nn;
    }
  }
}

// ---------------- combine: summ = (sum PN / sum PZ) * (mul ? mul : 1) ----------------
__global__ void summ_combine(const float* __restrict__ pz, const float* __restrict__ pn,
                             const float* __restrict__ mul, float* __restrict__ summ)
{
  int idx = blockIdx.x * 256 + threadIdx.x;  // 0..4095 : b*1024+e
  int b = idx >> 10, e = idx & 1023;
  float Z = 0.f, Nn = 0.f;
  for (int bm = b * 32; bm < b * 32 + 32; ++bm) {
    Z += pz[(size_t)bm * 1024 + e];
    Nn += pn[(size_t)bm * 1024 + e];
  }
  float r = Nn / Z;
  summ[idx] = mul ? r * mul[idx] : r;
}

// ---------------- elementwise ----------------
// GP8 = fp8(gelu_t(O * s1[b,:]))
__global__ void pk(const u16* __restrict__ O, const float* __restrict__ s1,
                   u8* __restrict__ GP8)
{
  size_t idx = (size_t)blockIdx.x * 256 + threadIdx.x;
  size_t base = idx * 8;
  int t = (int)(base >> 10);
  int b = t >> 12;
  int e = (int)(base & 1023);
  const float* sp = s1 + b * 1024 + e;
  u16x8 ov = *(const u16x8*)(O + base);
  float gv[8];
#pragma unroll
  for (int j = 0; j < 8; ++j) {
    gv[j] = gelu_t(bf2f(ov[j]) * sp[j]);
  }
  u32 lo = (cvtpk8(gv[0], gv[1]) & 0xFFFFu) | (cvtpk8(gv[2], gv[3]) << 16);
  u32 hi = (cvtpk8(gv[4], gv[5]) & 0xFFFFu) | (cvtpk8(gv[6], gv[7]) << 16);
  *(uint2*)(GP8 + base) = make_uint2(lo, hi);
}

// L = silu(G) * summ2[b,:]
__global__ void lk(const u16* __restrict__ G, const float* __restrict__ s2,
                   u16* __restrict__ L)
{
  size_t idx = (size_t)blockIdx.x * 256 + threadIdx.x;
  size_t base = idx * 8;
  int t = (int)(base >> 10);
  int b = t >> 12;
  int e = (int)(base & 1023);
  const float* sp = s2 + b * 1024 + e;
  u16x8 gvv = *(const u16x8*)(G + base);
  u16x8 lv;
#pragma unroll
  for (int j = 0; j < 8; ++j) {
    lv[j] = f2bf(siluf(bf2f(gvv[j])) * sp[j]);
  }
  *(u16x8*)(L + base) = lv;
}

// ---------------- launch ----------------
extern "C" void kernel_launch(void* const* d_in, const int* in_sizes, int n_in,
                              void* d_out, int out_size, void* d_ws, size_t ws_size,
                              hipStream_t stream)
{
  const float* x     = (const float*)d_in[0];
  const float* Wq    = (const float*)d_in[1];
  const float* Wqb   = (const float*)d_in[2];
  const float* Wo    = (const float*)d_in[3];
  const float* Wob   = (const float*)d_in[4];
  const float* Wg    = (const float*)d_in[5];
  const float* Wgb   = (const float*)d_in[6];
  const float* wa    = (const float*)d_in[7];
  const float* wb    = (const float*)d_in[8];
  const float* Wout  = (const float*)d_in[9];
  const float* Woutb = (const float*)d_in[10];
  const float* convw = (const float*)d_in[11];
  const float* convb = (const float*)d_in[12];

  char* ws = (char*)d_ws;
  size_t off = 0;
  auto alloc = [&](size_t bytes) -> char* {
    char* p = ws + off;
    off += (bytes + 255) & ~(size_t)255;
    return p;
  };

  u16* QPAD  = (u16*)alloc((size_t)4 * SPAD * 1024 * 2);  // bf16 Q, halo layout
  u8*  QPAD8 = (u8*)alloc((size_t)4 * SPAD * 1024);       // fp8 Q, halo layout (conv A)
  u16* OB   = (u16*)alloc((size_t)NT * 1024 * 2);         // O -> later L
  u16* GB   = (u16*)alloc((size_t)NT * 1024 * 2);         // G
  u16* XB   = (u16*)alloc((size_t)NT * 1024 * 2);         // x bf16 -> GA8 -> GP8
  u16* WALL = (u16*)alloc((size_t)4 * 1024 * 1024 * 2);   // bf16 [Wq,Wo,Wg,Wout]
  u8*  WAB8 = (u8*)alloc((size_t)2 * 1024 * 1024);        // fp8 [wa, wb] (unscaled)
  u8*  WC8  = (u8*)alloc((size_t)1024 * 3072);            // fp8 conv weights
  float* PZb = (float*)alloc((size_t)128 * 1024 * 4);     // per-m-tile softmax partials
  float* PNb = (float*)alloc((size_t)128 * 1024 * 4);
  float* S1 = (float*)alloc((size_t)4096 * 4);
  float* S2 = (float*)alloc((size_t)4096 * 4);

  if (off > ws_size) return;

  u16* WQ_    = WALL;
  u16* WO_    = WALL + (size_t)1 * 1048576;
  u16* WG_    = WALL + (size_t)2 * 1048576;
  u16* WOUTB_ = WALL + (size_t)3 * 1048576;
  u8*  WA8    = WAB8;
  u8*  WB8    = WAB8 + (size_t)1048576;

  u8* GA8 = (u8*)XB;   // conv output fp8 (x dead after Q/O/G)
  u8* GP8 = (u8*)XB;   // pk output fp8 (GA8 dead after wa-logits)
  u16* LB = OB;        // L aliases O (O dead after wb pass)

  const float scale = 0.03125f;  // 1/sqrt(1024)

  // 1. merged converts (x->bf16, weights, conv weights, halo zeroing both layouts)
  cvt_misc<<<26656, 256, 0, stream>>>(x, Wq, Wo, Wg, Wout, wa, wb, convw,
                                      XB, WALL, WAB8, WC8, QPAD, QPAD8);

  // 2. Q/O/G GEMMs (bf16); Q dual-writes bf16 halo + fp8 halo (kills cvt_q8)
  gemm128<1><<<128 * 8, 256, 0, stream>>>(XB, WQ_, QPAD, QPAD8, Wqb, NT, 1024, 1024, 1024);
  gemm128<0><<<128 * 8, 256, 0, stream>>>(XB, WO_, OB, nullptr, Wob, NT, 1024, 1024, 1024);
  gemm128<0><<<128 * 8, 256, 0, stream>>>(XB, WG_, GB, nullptr, Wgb, NT, 1024, 1024, 1024);

  // 3. conv as MX-fp8 GEMM (A = fp8 Qpad, K = 3072), epilogue gelu_t(silu(.)) -> GA8
  gemm128f8<2, 0><<<128 * 8, 256, 0, stream>>>(QPAD8, WC8, GA8, convb, 1.0f,
                                               nullptr, nullptr, nullptr,
                                               NT, 1024, 3072, 1024);

  // 4+5a. logits A + fused softmax partials (vals = QPAD bf16, halo remap)
  gemm128f8<5, 1><<<128 * 8, 256, 0, stream>>>(GA8, WA8, nullptr, nullptr, scale,
                                               QPAD, PZb, PNb,
                                               NT, 1024, 1024, 1024);
  summ_combine<<<16, 256, 0, stream>>>(PZb, PNb, nullptr, S1);

  // 6. GP8 = fp8(gelu_t(O * summ1))
  pk<<<8192, 256, 0, stream>>>(OB, S1, GP8);

  // 7+8a. logits B + fused softmax partials (vals = OB plain)
  gemm128f8<5, 0><<<128 * 8, 256, 0, stream>>>(GP8, WB8, nullptr, nullptr, scale,
                                               OB, PZb, PNb,
                                               NT, 1024, 1024, 1024);
  summ_combine<<<16, 256, 0, stream>>>(PZb, PNb, S1, S2);

  // 9. L = silu(G) * summ2
  lk<<<8192, 256, 0, stream>>>(GB, S2, LB);

  // 10. out = L @ Wout^T + b  (bf16 GEMM, f32 out)
  gemm128<3><<<128 * 8, 256, 0, stream>>>(LB, WOUTB_, d_out, nullptr, Woutb,
                                          NT, 1024, 1024, 1024);
}

// Round 13
// 350.612 us; speedup vs baseline: 1.0218x; 1.0218x over previous
//
#include <hip/hip_runtime.h>
#include <stdint.h>

#define DEV __device__ __forceinline__

typedef unsigned short u16;
typedef unsigned int u32;
typedef unsigned char u8;

typedef __bf16 bf16x8 __attribute__((ext_vector_type(8)));
typedef float f32x4 __attribute__((ext_vector_type(4)));
typedef u16 u16x8 __attribute__((ext_vector_type(8)));
typedef u16 u16x4 __attribute__((ext_vector_type(4)));
typedef u8 u8x8 __attribute__((ext_vector_type(8)));
typedef int i32x4 __attribute__((ext_vector_type(4)));
typedef int i32x8 __attribute__((ext_vector_type(8)));

static_assert(sizeof(bf16x8) == 16, "bf16x8 must be 16B");
static_assert(sizeof(i32x8) == 32, "i32x8 must be 32B");

#define NT 16384      // B*S = 4*4096
#define SPAD 4098     // S + 2 halo rows per batch

DEV u16 f2bf(float f) {
  u32 u = __float_as_uint(f);
  u32 r = u + 0x7FFFu + ((u >> 16) & 1u);
  return (u16)(r >> 16);
}
DEV float bf2f(u16 h) { return __uint_as_float(((u32)h) << 16); }
DEV float siluf(float x) { return x / (1.f + __expf(-x)); }

// tanh-gelu: used ONLY on the softmax-logit path (conv output, P-gelu)
DEV float gelu_t(float x) {
  float x2 = x * x;
  float z2 = x * (1.5957691216f + 0.0713548162f * x2);
  return x / (1.f + __expf(-z2));
}

// 2x f32 -> packed OCP e4m3 in low 16 bits (HW RNE+sat). low byte = src0.
DEV u32 cvtpk8(float a, float b) {
  u32 r;
  asm("v_cvt_pk_fp8_f32 %0, %1, %2" : "=v"(r) : "v"(a), "v"(b));
  return r;
}

DEV void gload_lds16(const void* g, void* l) {
  __builtin_amdgcn_global_load_lds((const __attribute__((address_space(1))) void*)g,
                                   (__attribute__((address_space(3))) void*)l,
                                   16, 0, 0);
}

DEV f32x4 mfma_mx(i32x8 a, i32x8 b, f32x4 c) {
  // fp8(e4m3) x fp8, unit scales (E8M0 127 = 2^0)
  return __builtin_amdgcn_mfma_scale_f32_16x16x128_f8f6f4(
      a, b, c, 0, 0, 0, 0x7F7F7F7Fu, 0, 0x7F7F7F7Fu);
}

// ---------------- merged converts ----------------
// [0,16384): x f32 -> XB bf16
// [16384,20480): Wq/Wo/Wg/Wout -> bf16 WALL
// [20480,22528): wa,wb -> fp8 WAB8
// [22528,26624): conv_w -> fp8 WC8 (tap-major)
// [26624,26656): zero halo rows of QPAD (bf16) and QPAD8 (fp8)
__global__ void cvt_misc(const float* __restrict__ x,
                         const float* __restrict__ Wq, const float* __restrict__ Wo,
                         const float* __restrict__ Wg, const float* __restrict__ Wout,
                         const float* __restrict__ wa, const float* __restrict__ wb,
                         const float* __restrict__ cw,
                         u16* __restrict__ XB,
                         u16* __restrict__ WALL, u8* __restrict__ WAB8,
                         u8* __restrict__ WC8, u16* __restrict__ QPAD,
                         u8* __restrict__ QPAD8)
{
  int bid = blockIdx.x, tid = threadIdx.x;
  if (bid < 16384) {
    int i = bid * 256 + tid;                        // 4,194,304 four-elem groups
    const float4 v = *(const float4*)(x + (size_t)i * 4);
    u16x4 o;
    o[0] = f2bf(v.x); o[1] = f2bf(v.y); o[2] = f2bf(v.z); o[3] = f2bf(v.w);
    *(u16x4*)(XB + (size_t)i * 4) = o;
  } else if (bid < 20480) {
    int idx = (bid - 16384) * 256 + tid;            // 4 * 262144
    int mat = idx >> 18, within = idx & 262143;
    const float* src = (mat == 0) ? Wq : (mat == 1) ? Wo : (mat == 2) ? Wg : Wout;
    const float4 v = *(const float4*)(src + (size_t)within * 4);
    u16x4 o;
    o[0] = f2bf(v.x); o[1] = f2bf(v.y); o[2] = f2bf(v.z); o[3] = f2bf(v.w);
    *(u16x4*)(WALL + (size_t)idx * 4) = o;
  } else if (bid < 22528) {
    int idx = (bid - 20480) * 256 + tid;            // 2 * 262144
    const float* src = (idx >> 18) ? wb : wa;
    int within = idx & 262143;
    const float4 v = *(const float4*)(src + (size_t)within * 4);
    u32 o = (cvtpk8(v.x, v.y) & 0xFFFFu) | (cvtpk8(v.z, v.w) << 16);
    *(u32*)(WAB8 + (size_t)idx * 4) = o;
  } else if (bid < 26624) {
    int i = (bid - 22528) * 256 + tid;              // 1M: o*1024+d
    int o = i >> 10, d = i & 1023;
    const float* src = cw + ((size_t)o * 1024 + d) * 3;
    u8* dst = WC8 + (size_t)o * 3072 + d;
    u32 w01 = cvtpk8(src[0], src[1]);
    u32 w2  = cvtpk8(src[2], src[2]);
    dst[0]    = (u8)(w01 & 0xFF);
    dst[1024] = (u8)((w01 >> 8) & 0xFF);
    dst[2048] = (u8)(w2 & 0xFF);
  } else {
    int i = (bid - 26624) * 256 + tid;              // 8192 threads
    int r = i >> 10, c = i & 1023;
    int b = r >> 1, side = r & 1;
    size_t row = (size_t)b * SPAD + (side ? (SPAD - 1) : 0);
    QPAD[row * 1024 + c] = 0;
    QPAD8[row * 1024 + c] = 0;
  }
}

// ================= gemm128: PROVEN bf16 structure (~888 TF) =================
// MODE 0: bf16 out (+bias). MODE 1: bf16 halo out + fp8 halo out to C2 (+bias).
// MODE 3: f32 out (+bias).
template<int MODE>
__global__ __launch_bounds__(256, 2)
void gemm128(const u16* __restrict__ A, const u16* __restrict__ B,
             void* __restrict__ C, void* __restrict__ C2, const float* __restrict__ bias,
             int M, int N, int K, int lda)
{
  __shared__ alignas(16) char smem[32768];
  char* sA = smem;
  char* sB = smem + 16384;

  int nwg = gridDim.x;
  int bx = blockIdx.x;
  if ((nwg & 7) == 0) bx = (bx & 7) * (nwg >> 3) + (bx >> 3);  // XCD swizzle (bijective)
  int GN = N >> 7;
  int bm = bx / GN, bn = bx - bm * GN;
  int m0 = bm << 7, n0 = bn << 7;

  int tid = threadIdx.x;
  int lane = tid & 63, wid = tid >> 6;
  int wm = wid >> 1, wn = wid & 1;

  f32x4 acc[4][4] = {};

  int strow = tid >> 3;            // 0..31
  int stcolb = (tid & 7) << 4;     // byte col 0..112
  size_t ldab = (size_t)lda * 2;
  size_t ldbb = (size_t)K * 2;

  const int KT = K >> 6;
  for (int kt = 0; kt < KT; ++kt) {
    int k0 = kt << 6;
    const char* Ab = (const char*)(A + ((size_t)m0 * (size_t)lda + k0));
    const char* Bb = (const char*)(B + ((size_t)n0 * (size_t)K + k0));
#pragma unroll
    for (int j = 0; j < 4; ++j) {
      int row = j * 32 + strow;
      int sw = (row & 7) << 4;     // XOR swizzle on 16B granules (involution)
      gload_lds16(Ab + (size_t)row * ldab + (size_t)(stcolb ^ sw), sA + j * 4096 + wid * 1024);
      gload_lds16(Bb + (size_t)row * ldbb + (size_t)(stcolb ^ sw), sB + j * 4096 + wid * 1024);
    }
    __syncthreads();
#pragma unroll
    for (int kk = 0; kk < 2; ++kk) {
      bf16x8 av[4], bv[4];
      int cb = ((lane >> 4) << 4) + (kk << 6);
#pragma unroll
      for (int i = 0; i < 4; ++i) {
        int r = (wm << 6) + (i << 4) + (lane & 15);
        av[i] = *(const bf16x8*)(sA + r * 128 + (cb ^ ((r & 7) << 4)));
      }
#pragma unroll
      for (int j = 0; j < 4; ++j) {
        int r = (wn << 6) + (j << 4) + (lane & 15);
        bv[j] = *(const bf16x8*)(sB + r * 128 + (cb ^ ((r & 7) << 4)));
      }
#pragma unroll
      for (int i = 0; i < 4; ++i)
#pragma unroll
        for (int j = 0; j < 4; ++j)
          acc[i][j] = __builtin_amdgcn_mfma_f32_16x16x32_bf16(av[i], bv[j], acc[i][j], 0, 0, 0);
    }
    __syncthreads();
  }

  // epilogue: frag row=(lane>>4)*4+r, col=lane&15
#pragma unroll
  for (int i = 0; i < 4; ++i) {
    int rb = m0 + (wm << 6) + (i << 4) + ((lane >> 4) << 2);
#pragma unroll
    for (int j = 0; j < 4; ++j) {
      int n = n0 + (wn << 6) + (j << 4) + (lane & 15);
      float bs = bias ? bias[n] : 0.f;
      if (MODE == 1) {
        float v0 = acc[i][j][0] + bs, v1 = acc[i][j][1] + bs;
        float v2 = acc[i][j][2] + bs, v3 = acc[i][j][3] + bs;
        size_t row0 = (size_t)rb + 2 * (rb >> 12) + 1;
        u16* cb16 = (u16*)C + row0 * 1024 + n;
        cb16[0]    = f2bf(v0);
        cb16[1024] = f2bf(v1);
        cb16[2048] = f2bf(v2);
        cb16[3072] = f2bf(v3);
        u32 w01 = cvtpk8(v0, v1);
        u32 w23 = cvtpk8(v2, v3);
        u8* c8 = (u8*)C2 + row0 * 1024 + n;
        c8[0]    = (u8)(w01 & 0xFF);
        c8[1024] = (u8)((w01 >> 8) & 0xFF);
        c8[2048] = (u8)(w23 & 0xFF);
        c8[3072] = (u8)((w23 >> 8) & 0xFF);
      } else {
#pragma unroll
        for (int r = 0; r < 4; ++r) {
          int t = rb + r;
          float v = acc[i][j][r] + bs;
          if (MODE == 0) ((u16*)C)[(size_t)t * N + n] = f2bf(v);
          else           ((float*)C)[(size_t)t * N + n] = v;
        }
      }
    }
  }
}

// ================= gemm128f8: MX-fp8, conflict-free half-swizzle, BK=128 =================
// LDS bijection: half h of granule (row r, 32B-col cb) at
//   r*128 + (cb ^ ((r&3)<<5)) + 16*(h ^ ((r>>2)&1)); linear dest, source solves it.
// Low-VGPR MFMA loop: av[4] resident, bv built just-in-time -> unified regs fit 128
// (4 waves/SIMD, enforced by __launch_bounds__(256,4)).
// MODE 2: conv (A = fp8 Qpad halo), epilogue gelu_t(silu(v+b)) -> fp8.
// MODE 5: fused logits+softmax-partial -> PZp/PNp[m_tile][col].
template<int MODE, int VREMAP>
__global__ __launch_bounds__(256, 4)
void gemm128f8(const u8* __restrict__ A, const u8* __restrict__ B,
               void* __restrict__ C, const float* __restrict__ bias, float episcale,
               const u16* __restrict__ vals, float* __restrict__ PZp, float* __restrict__ PNp,
               int M, int N, int K, int lda /*bytes*/)
{
  __shared__ alignas(32) char smem[32768];
  char* sA = smem;
  char* sB = smem + 16384;

  int nwg = gridDim.x;
  int bx = blockIdx.x;
  if ((nwg & 7) == 0) bx = (bx & 7) * (nwg >> 3) + (bx >> 3);
  int GN = N >> 7;
  int bm = bx / GN, bn = bx - bm * GN;
  int m0 = bm << 7, n0 = bn << 7;

  int tid = threadIdx.x;
  int lane = tid & 63, wid = tid >> 6;
  int wm = wid >> 1, wn = wid & 1;

  f32x4 acc[4][4] = {};

  int strow = tid >> 3;            // 0..31 (row within 32-row chunk)
  int g = (tid >> 1) & 3, p = tid & 1;
  int srccol = (((g ^ (strow & 3)) << 5) | ((p ^ ((strow >> 2) & 1)) << 4));
  int bofm = m0 >> 12;

  // incremental bases + kt-invariant per-thread offsets
  const char* Ab = (const char*)A + (size_t)(m0 + (MODE == 2 ? 2 * bofm : 0)) * lda;
  const char* Bb = (const char*)B + (size_t)n0 * K;
  size_t offA[4], offB[4];
#pragma unroll
  for (int j = 0; j < 4; ++j) {
    offA[j] = (size_t)(j * 32 + strow) * lda + srccol;
    offB[j] = (size_t)(j * 32 + strow) * K + srccol;
  }
  int dstL[4];
#pragma unroll
  for (int j = 0; j < 4; ++j) dstL[j] = j * 4096 + wid * 1024;

  const int KT = K >> 7;           // BK = 128 (bytes == elements)
  for (int kt = 0; kt < KT; ++kt) {
#pragma unroll
    for (int j = 0; j < 4; ++j) {
      gload_lds16(Ab + offA[j], sA + dstL[j]);
      gload_lds16(Bb + offB[j], sB + dstL[j]);
    }
    __syncthreads();
    {
      int cb = (lane >> 4) << 5;   // 32B K-chunk per lane group (one MX block)
      i32x8 av[4];
#pragma unroll
      for (int i = 0; i < 4; ++i) {
        int r = (wm << 6) + (i << 4) + (lane & 15);
        int base = r * 128 + (cb ^ ((r & 3) << 5));
        int b2 = ((r >> 2) & 1) << 4;
        i32x4 lo = *(const i32x4*)(sA + base + b2);          // half 0
        i32x4 hi = *(const i32x4*)(sA + base + (b2 ^ 16));   // half 1
        av[i] = i32x8{lo[0], lo[1], lo[2], lo[3], hi[0], hi[1], hi[2], hi[3]};
      }
#pragma unroll
      for (int j = 0; j < 4; ++j) {
        int r = (wn << 6) + (j << 4) + (lane & 15);
        int base = r * 128 + (cb ^ ((r & 3) << 5));
        int b2 = ((r >> 2) & 1) << 4;
        i32x4 lo = *(const i32x4*)(sB + base + b2);
        i32x4 hi = *(const i32x4*)(sB + base + (b2 ^ 16));
        i32x8 bv = i32x8{lo[0], lo[1], lo[2], lo[3], hi[0], hi[1], hi[2], hi[3]};
#pragma unroll
        for (int i = 0; i < 4; ++i)
          acc[i][j] = mfma_mx(av[i], bv, acc[i][j]);
      }
    }
    __syncthreads();
    Ab += 128; Bb += 128;          // linear walk (conv taps included)
  }

  if (MODE == 2) {
#pragma unroll
    for (int i = 0; i < 4; ++i) {
      int rb = m0 + (wm << 6) + (i << 4) + ((lane >> 4) << 2);
#pragma unroll
      for (int j = 0; j < 4; ++j) {
        int n = n0 + (wn << 6) + (j << 4) + (lane & 15);
        float bs = bias ? bias[n] : 0.f;
        float g0 = gelu_t(siluf(acc[i][j][0] + bs));
        float g1 = gelu_t(siluf(acc[i][j][1] + bs));
        float g2 = gelu_t(siluf(acc[i][j][2] + bs));
        float g3 = gelu_t(siluf(acc[i][j][3] + bs));
        u32 w01 = cvtpk8(g0, g1);
        u32 w23 = cvtpk8(g2, g3);
        u8* cp = (u8*)C + (size_t)rb * N + n;
        cp[0]            = (u8)(w01 & 0xFF);
        cp[(size_t)N]    = (u8)((w01 >> 8) & 0xFF);
        cp[(size_t)N*2]  = (u8)(w23 & 0xFF);
        cp[(size_t)N*3]  = (u8)((w23 >> 8) & 0xFF);
      }
    }
  } else {  // MODE 5: fused softmax partial (no max subtraction; logits are tiny)
    float zj[4] = {0.f, 0.f, 0.f, 0.f}, nj[4] = {0.f, 0.f, 0.f, 0.f};
#pragma unroll
    for (int i = 0; i < 4; ++i) {
      int rb = m0 + (wm << 6) + (i << 4) + ((lane >> 4) << 2);
#pragma unroll
      for (int j = 0; j < 4; ++j) {
        int n = n0 + (wn << 6) + (j << 4) + (lane & 15);
#pragma unroll
        for (int r = 0; r < 4; ++r) {
          int t = rb + r;
          float w = __expf(acc[i][j][r] * episcale);
          size_t vrow = VREMAP ? ((size_t)t + 2 * (t >> 12) + 1) : (size_t)t;
          float v = bf2f(vals[vrow * 1024 + n]);
          zj[j] += w;
          nj[j] += v * w;
        }
      }
    }
    __syncthreads();                 // LDS free after K-loop's trailing sync + this
    float2* arr = (float2*)smem;     // [128 cols][8 contributors]
    int gg = (wm << 2) + (lane >> 4); // 0..7
#pragma unroll
    for (int j = 0; j < 4; ++j) {
      int cl = (wn << 6) + (j << 4) + (lane & 15);   // 0..127
      arr[cl * 8 + gg] = make_float2(zj[j], nj[j]);
    }
    __syncthreads();
    if (tid < 128) {
      float Z = 0.f, Nn = 0.f;
#pragma unroll
      for (int g2 = 0; g2 < 8; ++g2) { float2 q = arr[tid * 8 + g2]; Z += q.x; Nn += q.y; }
      size_t o = (size_t)(m0 >> 7) * 1024 + n0 + tid;
      PZp[o] = Z;
      PNp[o] = Nn;
    }
  }
}

// ---------------- combine: summ = (sum PN / sum PZ) * (mul ? mul : 1) ----------------
__global__ void summ_combine(const float* __restrict__ pz, const float* __restrict__ pn,
                             const float* __restrict__ mul, float* __restrict__ summ)
{
  int idx = blockIdx.x * 256 + threadIdx.x;  // 0..4095 : b*1024+e
  int b = idx >> 10, e = idx & 1023;
  float Z = 0.f, Nn = 0.f;
  for (int bm = b * 32; bm < b * 32 + 32; ++bm) {
    Z += pz[(size_t)bm * 1024 + e];
    Nn += pn[(size_t)bm * 1024 + e];
  }
  float r = Nn / Z;
  summ[idx] = mul ? r * mul[idx] : r;
}

// ---------------- elementwise ----------------
// GP8 = fp8(gelu_t(O * s1[b,:]))
__global__ void pk(const u16* __restrict__ O, const float* __restrict__ s1,
                   u8* __restrict__ GP8)
{
  size_t idx = (size_t)blockIdx.x * 256 + threadIdx.x;
  size_t base = idx * 8;
  int t = (int)(base >> 10);
  int b = t >> 12;
  int e = (int)(base & 1023);
  const float* sp = s1 + b * 1024 + e;
  u16x8 ov = *(const u16x8*)(O + base);
  float gv[8];
#pragma unroll
  for (int j = 0; j < 8; ++j) {
    gv[j] = gelu_t(bf2f(ov[j]) * sp[j]);
  }
  u32 lo = (cvtpk8(gv[0], gv[1]) & 0xFFFFu) | (cvtpk8(gv[2], gv[3]) << 16);
  u32 hi = (cvtpk8(gv[4], gv[5]) & 0xFFFFu) | (cvtpk8(gv[6], gv[7]) << 16);
  *(uint2*)(GP8 + base) = make_uint2(lo, hi);
}

// L = silu(G) * summ2[b,:]
__global__ void lk(const u16* __restrict__ G, const float* __restrict__ s2,
                   u16* __restrict__ L)
{
  size_t idx = (size_t)blockIdx.x * 256 + threadIdx.x;
  size_t base = idx * 8;
  int t = (int)(base >> 10);
  int b = t >> 12;
  int e = (int)(base & 1023);
  const float* sp = s2 + b * 1024 + e;
  u16x8 gvv = *(const u16x8*)(G + base);
  u16x8 lv;
#pragma unroll
  for (int j = 0; j < 8; ++j) {
    lv[j] = f2bf(siluf(bf2f(gvv[j])) * sp[j]);
  }
  *(u16x8*)(L + base) = lv;
}

// ---------------- launch ----------------
extern "C" void kernel_launch(void* const* d_in, const int* in_sizes, int n_in,
                              void* d_out, int out_size, void* d_ws, size_t ws_size,
                              hipStream_t stream)
{
  const float* x     = (const float*)d_in[0];
  const float* Wq    = (const float*)d_in[1];
  const float* Wqb   = (const float*)d_in[2];
  const float* Wo    = (const float*)d_in[3];
  const float* Wob   = (const float*)d_in[4];
  const float* Wg    = (const float*)d_in[5];
  const float* Wgb   = (const float*)d_in[6];
  const float* wa    = (const float*)d_in[7];
  const float* wb    = (const float*)d_in[8];
  const float* Wout  = (const float*)d_in[9];
  const float* Woutb = (const float*)d_in[10];
  const float* convw = (const float*)d_in[11];
  const float* convb = (const float*)d_in[12];

  char* ws = (char*)d_ws;
  size_t off = 0;
  auto alloc = [&](size_t bytes) -> char* {
    char* p = ws + off;
    off += (bytes + 255) & ~(size_t)255;
    return p;
  };

  u16* QPAD  = (u16*)alloc((size_t)4 * SPAD * 1024 * 2);  // bf16 Q, halo layout
  u8*  QPAD8 = (u8*)alloc((size_t)4 * SPAD * 1024);       // fp8 Q, halo layout (conv A)
  u16* OB   = (u16*)alloc((size_t)NT * 1024 * 2);         // O -> later L
  u16* GB   = (u16*)alloc((size_t)NT * 1024 * 2);         // G
  u16* XB   = (u16*)alloc((size_t)NT * 1024 * 2);         // x bf16 -> GA8 -> GP8
  u16* WALL = (u16*)alloc((size_t)4 * 1024 * 1024 * 2);   // bf16 [Wq,Wo,Wg,Wout]
  u8*  WAB8 = (u8*)alloc((size_t)2 * 1024 * 1024);        // fp8 [wa, wb] (unscaled)
  u8*  WC8  = (u8*)alloc((size_t)1024 * 3072);            // fp8 conv weights
  float* PZb = (float*)alloc((size_t)128 * 1024 * 4);     // per-m-tile softmax partials
  float* PNb = (float*)alloc((size_t)128 * 1024 * 4);
  float* S1 = (float*)alloc((size_t)4096 * 4);
  float* S2 = (float*)alloc((size_t)4096 * 4);

  if (off > ws_size) return;

  u16* WQ_    = WALL;
  u16* WO_    = WALL + (size_t)1 * 1048576;
  u16* WG_    = WALL + (size_t)2 * 1048576;
  u16* WOUTB_ = WALL + (size_t)3 * 1048576;
  u8*  WA8    = WAB8;
  u8*  WB8    = WAB8 + (size_t)1048576;

  u8* GA8 = (u8*)XB;   // conv output fp8 (x dead after Q/O/G)
  u8* GP8 = (u8*)XB;   // pk output fp8 (GA8 dead after wa-logits)
  u16* LB = OB;        // L aliases O (O dead after wb pass)

  const float scale = 0.03125f;  // 1/sqrt(1024)

  // 1. merged converts (x->bf16, weights, conv weights, halo zeroing both layouts)
  cvt_misc<<<26656, 256, 0, stream>>>(x, Wq, Wo, Wg, Wout, wa, wb, convw,
                                      XB, WALL, WAB8, WC8, QPAD, QPAD8);

  // 2. Q/O/G GEMMs (bf16); Q dual-writes bf16 halo + fp8 halo
  gemm128<1><<<128 * 8, 256, 0, stream>>>(XB, WQ_, QPAD, QPAD8, Wqb, NT, 1024, 1024, 1024);
  gemm128<0><<<128 * 8, 256, 0, stream>>>(XB, WO_, OB, nullptr, Wob, NT, 1024, 1024, 1024);
  gemm128<0><<<128 * 8, 256, 0, stream>>>(XB, WG_, GB, nullptr, Wgb, NT, 1024, 1024, 1024);

  // 3. conv as MX-fp8 GEMM (A = fp8 Qpad, K = 3072), epilogue gelu_t(silu(.)) -> GA8
  gemm128f8<2, 0><<<128 * 8, 256, 0, stream>>>(QPAD8, WC8, GA8, convb, 1.0f,
                                               nullptr, nullptr, nullptr,
                                               NT, 1024, 3072, 1024);

  // 4+5a. logits A + fused softmax partials (vals = QPAD bf16, halo remap)
  gemm128f8<5, 1><<<128 * 8, 256, 0, stream>>>(GA8, WA8, nullptr, nullptr, scale,
                                               QPAD, PZb, PNb,
                                               NT, 1024, 1024, 1024);
  summ_combine<<<16, 256, 0, stream>>>(PZb, PNb, nullptr, S1);

  // 6. GP8 = fp8(gelu_t(O * summ1))
  pk<<<8192, 256, 0, stream>>>(OB, S1, GP8);

  // 7+8a. logits B + fused softmax partials (vals = OB plain)
  gemm128f8<5, 0><<<128 * 8, 256, 0, stream>>>(GP8, WB8, nullptr, nullptr, scale,
                                               OB, PZb, PNb,
                                               NT, 1024, 1024, 1024);
  summ_combine<<<16, 256, 0, stream>>>(PZb, PNb, S1, S2);

  // 9. L = silu(G) * summ2
  lk<<<8192, 256, 0, stream>>>(GB, S2, LB);

  // 10. out = L @ Wout^T + b  (bf16 GEMM, f32 out)
  gemm128<3><<<128 * 8, 256, 0, stream>>>(LB, WOUTB_, d_out, nullptr, Woutb,
                                          NT, 1024, 1024, 1024);
}